// Round 8
// baseline (924.389 us; speedup 1.0000x reference)
//
#include <hip/hip_runtime.h>
#include <hip/hip_bf16.h>
#include <cstdint>

#define DIMc 1024
#define HIDc 2048
#define NTOK 8192
#define NRT 6

typedef __bf16 bf16x8 __attribute__((ext_vector_type(8)));
typedef __bf16 bf16x2v __attribute__((ext_vector_type(2)));
typedef float  f32x4  __attribute__((ext_vector_type(4)));

#define VMCNT(n) asm volatile("s_waitcnt vmcnt(" #n ")" ::: "memory")
#define RBAR()   asm volatile("s_barrier" ::: "memory")

__device__ __forceinline__ void gl_lds16(const void* gsrc, void* ldst) {
    auto g = (const __attribute__((address_space(1))) void*)gsrc;
    auto l = (__attribute__((address_space(3))) void*)ldst;
    __builtin_amdgcn_global_load_lds(g, l, 16, 0, 0);
}

// T1 bijective XCD swizzle (m204)
__device__ __forceinline__ void xcd_swz(int lid, int nwg, int gx, int& bx, int& by) {
    int q = nwg >> 3, r = nwg & 7;
    int xcd = lid & 7, idx = lid >> 3;
    int nlid = (xcd < r ? xcd * (q + 1) : r * (q + 1) + (xcd - r) * q) + idx;
    bx = nlid % gx; by = nlid / gx;
}

// ---------------- transpose + fp32->bf16 convert for all weights ----------------
__global__ __launch_bounds__(256) void tcvt_k(
    const float* __restrict__ w1s, const float* __restrict__ w2s, const float* __restrict__ w3s,
    const float* __restrict__ w1r, const float* __restrict__ w2r, const float* __restrict__ w3r,
    const float* __restrict__ outw,
    __bf16* __restrict__ W13T, __bf16* __restrict__ W2T, __bf16* __restrict__ OutWT)
{
    int id = blockIdx.z;
    const float* src; __bf16* dst; int K, N; size_t S;
    if (id < 4) {
        int half = id >> 1, ex = id & 1;
        src = (half ? w3s : w1s) + (size_t)ex * DIMc * HIDc;
        K = 1024; N = 2048; S = 1024;
        dst = W13T + ((size_t)half * 4096 + ex * 2048) * 1024;
    } else if (id < 16) {
        int j = id - 4; int ex = j >> 1, half = j & 1;
        src = (half ? w3r : w1r) + (size_t)ex * DIMc * HIDc;
        K = 1024; N = 2048; S = 1024;
        dst = W13T + ((size_t)8192 + ex * 4096 + half * 2048) * 1024;
    } else if (id < 18) {
        int ex = id - 16;
        src = w2s + (size_t)ex * HIDc * DIMc;
        K = 2048; N = 1024; S = 4096;
        dst = W2T + ex * 2048;
    } else if (id < 24) {
        int ex = id - 18;
        src = w2r + (size_t)ex * HIDc * DIMc;
        K = 2048; N = 1024; S = 2048;
        dst = W2T + (size_t)4096 * 1024 + (size_t)ex * 2048 * 1024;
    } else {
        src = outw; K = 1024; N = 1024; S = 1024; dst = OutWT;
    }
    int n0 = blockIdx.x * 32, k0 = blockIdx.y * 32;
    if (n0 >= N || k0 >= K) return;
    __shared__ float t[32][33];
    int c = threadIdx.x & 31, rb = threadIdx.x >> 5;
#pragma unroll
    for (int i = 0; i < 4; i++) {
        int r = rb + i * 8;
        t[r][c] = src[(size_t)(k0 + r) * N + n0 + c];
    }
    __syncthreads();
    int kp = threadIdx.x & 15, nn = threadIdx.x >> 4;
#pragma unroll
    for (int pass = 0; pass < 2; pass++) {
        int n = nn + pass * 16;
        bf16x2v v; v[0] = (__bf16)t[2 * kp][n]; v[1] = (__bf16)t[2 * kp + 1][n];
        *(bf16x2v*)&dst[(size_t)(n0 + n) * S + k0 + 2 * kp] = v;
    }
}

// ---------------- router ----------------
__global__ __launch_bounds__(256) void router_k(
    const float* __restrict__ x, const float* __restrict__ gate,
    __bf16* __restrict__ xb, int* __restrict__ tke, float* __restrict__ tkw,
    float* __restrict__ auxp, float* __restrict__ auxf, int* __restrict__ rcnt)
{
    __shared__ float gl[DIMc * NRT];
    __shared__ float pacc[NRT];
    __shared__ int hist1[NRT], hist2[NRT];
    for (int i = threadIdx.x; i < DIMc * NRT; i += 256) gl[i] = gate[i];
    if (threadIdx.x < NRT) { pacc[threadIdx.x] = 0.f; hist1[threadIdx.x] = 0; hist2[threadIdx.x] = 0; }
    __syncthreads();
    int lane = threadIdx.x & 63, wid = threadIdx.x >> 6;
    for (int rep = 0; rep < 4; rep++) {
        int t = blockIdx.x * 16 + wid * 4 + rep;
        float a[NRT] = {0.f, 0.f, 0.f, 0.f, 0.f, 0.f};
        const float* xr = x + (size_t)t * DIMc;
        __bf16* xbr = xb + (size_t)t * DIMc;
        for (int k = lane; k < DIMc; k += 64) {
            float v = xr[k];
            xbr[k] = (__bf16)v;
#pragma unroll
            for (int e = 0; e < NRT; e++) a[e] += v * gl[k * NRT + e];
        }
#pragma unroll
        for (int e = 0; e < NRT; e++)
#pragma unroll
            for (int m = 32; m; m >>= 1) a[e] += __shfl_xor(a[e], m);
        if (lane == 0) {
            int i0 = 0; float m0 = a[0];
#pragma unroll
            for (int e = 1; e < NRT; e++) if (a[e] > m0) { m0 = a[e]; i0 = e; }
            int i1 = -1; float m1 = -1e30f;
#pragma unroll
            for (int e = 0; e < NRT; e++) if (e != i0 && a[e] > m1) { m1 = a[e]; i1 = e; }
            float w1 = __expf(m1 - m0);
            float inv = 1.f / (1.f + w1);
            tke[2 * t] = i0; tke[2 * t + 1] = i1;
            tkw[2 * t] = inv; tkw[2 * t + 1] = w1 * inv;
            float se = 0.f, pe[NRT];
#pragma unroll
            for (int e = 0; e < NRT; e++) { pe[e] = __expf(a[e] - m0); se += pe[e]; }
            float rinv = 1.f / se;
#pragma unroll
            for (int e = 0; e < NRT; e++) atomicAdd(&pacc[e], pe[e] * rinv);
            atomicAdd(&hist1[i0], 1);
            atomicAdd(&hist2[i0], 1); atomicAdd(&hist2[i1], 1);
        }
    }
    __syncthreads();
    if (threadIdx.x < NRT) {
        atomicAdd(&auxp[threadIdx.x], pacc[threadIdx.x]);
        atomicAdd(&auxf[threadIdx.x], (float)hist1[threadIdx.x]);
        atomicAdd(&rcnt[threadIdx.x], hist2[threadIdx.x]);
    }
}

__global__ void offsets_k(const int* __restrict__ rcnt, int* __restrict__ goff, int* __restrict__ gcnt) {
    if (threadIdx.x == 0) {
        int off = 0;
        for (int e = 0; e < NRT; e++) { goff[e] = off; gcnt[e] = rcnt[e]; off += rcnt[e]; }
    }
}

__global__ __launch_bounds__(256) void scatter_k(
    const int* __restrict__ tke, const float* __restrict__ tkw,
    const int* __restrict__ goff, int* __restrict__ curs,
    int* __restrict__ perm, float* __restrict__ wrow, int* __restrict__ islot)
{
    int t = blockIdx.x * 256 + threadIdx.x;
    if (t >= NTOK) return;
#pragma unroll
    for (int k = 0; k < 2; k++) {
        int e = tke[2 * t + k]; float w = tkw[2 * t + k];
        int slot = atomicAdd(&curs[e], 1);
        int sr = goff[e] + slot;
        perm[sr] = t; wrow[sr] = w; islot[2 * t + k] = sr;
    }
}

__global__ void auxfin_k(const float* __restrict__ auxp, const float* __restrict__ auxf, float* __restrict__ out) {
    if (threadIdx.x == 0) {
        float s = 0.f;
        for (int e = 0; e < NRT; e++) s += (auxf[e] * (1.f / NTOK)) * (auxp[e] * (1.f / NTOK));
        out[(size_t)NTOK * DIMc] = 0.01f * 6.f * s;
    }
}

// ---------------- dual-GEMM silu: 256(M)x128(colpairs) tile, BK=32, depth-3 ring, 512 thr ----------------
// B-tile 256 rows interleaved per-16: group g=jr>>5, s=jr&31; s<16 -> h1 row, s>=16 -> h3 row (same cols).
// Waves 2M x 4N: per-wave 128 rows x 64 B-rows (= 32 col-pairs). acc[8][4]; ni even=h1, odd=h3.
template <int SHARED>
__global__ __launch_bounds__(512, 2) void gemm13_k(
    const __bf16* __restrict__ A, const __bf16* __restrict__ W13, __bf16* __restrict__ gbuf,
    const int* __restrict__ goff, const int* __restrict__ gcnt, const int* __restrict__ perm)
{
    __shared__ __bf16 lds[4 * 16384];   // 4 slots x (A 8192 | B 8192) = 128 KB
    int cnt, gofs, h3row, gstride;
    const __bf16* Bg;
    if constexpr (SHARED) {
        cnt = NTOK; gofs = 0; h3row = 4096; gstride = 4096; Bg = W13;
    } else {
        int e = blockIdx.z;
        cnt = gcnt[e]; gofs = goff[e]; h3row = 2048; gstride = 2048;
        Bg = W13 + ((size_t)8192 + (size_t)e * 4096) * 1024;
    }
    int bx, by;
    xcd_swz(blockIdx.x + gridDim.x * blockIdx.y, gridDim.x * gridDim.y, gridDim.x, bx, by);
    if (bx * 256 >= cnt) return;
    const int tid = threadIdx.x;
    const int lane = tid & 63, wid = tid >> 6;
    const int wr = wid >> 2, wc = wid & 3;        // 2M x 4N
    const int l15 = lane & 15, l4 = lane >> 4;

    // staging pointers: A chunks (1024 = 2/thr), B chunks (1024 = 2/thr); chunk: row=c>>2, q=c&3 (16B)
    const __bf16* agA[2]; const __bf16* agB[2];
    int ldsA[2], ldsB[2];
#pragma unroll
    for (int i = 0; i < 2; i++) {
        int cA = i * 512 + tid;
        int rowA = cA >> 2, qA = cA & 3;
        int r = bx * 256 + rowA; if (r > cnt - 1) r = cnt - 1;
        size_t arow = SHARED ? (size_t)r : (size_t)perm[gofs + r];
        agA[i] = A + arow * 1024 + qA * 8;
        ldsA[i] = cA * 8;
        int cB = i * 512 + tid;
        int jr = cB >> 2, qB = cB & 3;
        int g = jr >> 5, s = jr & 31;
        int r1 = by * 128 + g * 16 + (s & 15);
        int brow = (s < 16) ? r1 : (h3row + r1);
        agB[i] = Bg + (size_t)brow * 1024 + qB * 8;
        ldsB[i] = cB * 8;
    }

#define STG13(slot, kt) { __bf16* d_ = lds + (slot) * 16384; \
    gl_lds16(agA[0] + (kt) * 32, d_ + ldsA[0]); \
    gl_lds16(agA[1] + (kt) * 32, d_ + ldsA[1]); \
    gl_lds16(agB[0] + (kt) * 32, d_ + 8192 + ldsB[0]); \
    gl_lds16(agB[1] + (kt) * 32, d_ + 8192 + ldsB[1]); }

    f32x4 acc[8][4];
#pragma unroll
    for (int mi = 0; mi < 8; mi++)
#pragma unroll
        for (int ni = 0; ni < 4; ni++)
#pragma unroll
            for (int j = 0; j < 4; j++) acc[mi][ni][j] = 0.f;

#define CMP13(slot) { \
    const __bf16* As = lds + (slot) * 16384; \
    const __bf16* Bs = As + 8192; \
    bf16x8 av[8], bv[4]; \
    _Pragma("unroll") for (int mi = 0; mi < 8; mi++) \
        av[mi] = *(const bf16x8*)&As[(wr * 128 + mi * 16 + l15) * 32 + l4 * 8]; \
    _Pragma("unroll") for (int ni = 0; ni < 4; ni++) \
        bv[ni] = *(const bf16x8*)&Bs[(wc * 64 + ni * 16 + l15) * 32 + l4 * 8]; \
    __builtin_amdgcn_s_setprio(1); \
    _Pragma("unroll") for (int mi = 0; mi < 8; mi++) \
        _Pragma("unroll") for (int ni = 0; ni < 4; ni++) \
            acc[mi][ni] = __builtin_amdgcn_mfma_f32_16x16x32_bf16(av[mi], bv[ni], acc[mi][ni], 0, 0, 0); \
    __builtin_amdgcn_s_setprio(0); }

    const int nkt = 32;   // K=1024 / BK=32
    STG13(0, 0); STG13(1, 1); STG13(2, 2);
    int kt = 0;
    for (; kt < nkt - 3; kt++) {
        VMCNT(8); RBAR();
        STG13((kt + 3) & 3, kt + 3);
        CMP13(kt & 3);
    }
    VMCNT(8); RBAR(); CMP13(kt & 3); kt++;
    VMCNT(4); RBAR(); CMP13(kt & 3); kt++;
    VMCNT(0); RBAR(); CMP13(kt & 3);

#pragma unroll
    for (int mi = 0; mi < 8; mi++) {
#pragma unroll
        for (int j = 0; j < 4; j++) {
            int r = bx * 256 + wr * 128 + mi * 16 + l4 * 4 + j;
            if (r < cnt) {
                size_t orow = (size_t)(gofs + r) * gstride;
#pragma unroll
                for (int p = 0; p < 2; p++) {
                    int c = by * 128 + wc * 32 + p * 16 + l15;
                    float h1 = acc[mi][2 * p][j], h3 = acc[mi][2 * p + 1][j];
                    float sg = h1 / (1.f + __expf(-h1));
                    gbuf[orow + c] = (__bf16)(sg * h3);
                }
            }
        }
    }
#undef STG13
#undef CMP13
}

// ---------------- single GEMM: 256(M)x128(N) tile, BK=32, depth-3 ring, 512 thr ----------------
// MODE 0: shared w2 (K=4096, out ybuf bf16). MODE 1: routed w2 (K=2048, out ybuf[8192+sr]*w).
// MODE 2: out-proj (K=1024, out fp32). Waves 4M x 2N: per-wave 64 rows x 64 cols, acc[4][4].
template <int MODE>
__global__ __launch_bounds__(512, 2) void gemmNN_k(
    const __bf16* __restrict__ A, const __bf16* __restrict__ B,
    __bf16* __restrict__ outB16, float* __restrict__ outF32,
    const float* __restrict__ wrow, const int* __restrict__ goff, const int* __restrict__ gcnt,
    int K)
{
    __shared__ __bf16 lds[4 * 12288];   // 4 slots x (A 8192 | B 4096) = 96 KB
    int cnt, gofs;
    const __bf16* Bg;
    if constexpr (MODE == 1) {
        int e = blockIdx.z;
        cnt = gcnt[e]; gofs = goff[e];
        Bg = B + (size_t)e * 2048 * 1024;
    } else {
        cnt = NTOK; gofs = 0; Bg = B;
    }
    int bx, by;
    xcd_swz(blockIdx.x + gridDim.x * blockIdx.y, gridDim.x * gridDim.y, gridDim.x, bx, by);
    if (bx * 256 >= cnt) return;
    const int tid = threadIdx.x;
    const int lane = tid & 63, wid = tid >> 6;
    const int wr = wid >> 1, wc = wid & 1;        // 4M x 2N
    const int l15 = lane & 15, l4 = lane >> 4;

    const __bf16* agA[2]; const __bf16* agB1;
    int ldsA[2], ldsB1;
#pragma unroll
    for (int i = 0; i < 2; i++) {
        int cA = i * 512 + tid;
        int rowA = cA >> 2, qA = cA & 3;
        int r = bx * 256 + rowA; if (r > cnt - 1) r = cnt - 1;
        agA[i] = A + (size_t)(gofs + r) * K + qA * 8;
        ldsA[i] = cA * 8;
    }
    {
        int cB = tid;                      // 512 chunks: rows 0..127
        int jr = cB >> 2, qB = cB & 3;
        agB1 = Bg + (size_t)(by * 128 + jr) * K + qB * 8;
        ldsB1 = cB * 8;
    }

#define STGNN(slot, kt) { __bf16* d_ = lds + (slot) * 12288; \
    gl_lds16(agA[0] + (kt) * 32, d_ + ldsA[0]); \
    gl_lds16(agA[1] + (kt) * 32, d_ + ldsA[1]); \
    gl_lds16(agB1 + (kt) * 32, d_ + 8192 + ldsB1); }

    f32x4 acc[4][4];
#pragma unroll
    for (int mi = 0; mi < 4; mi++)
#pragma unroll
        for (int ni = 0; ni < 4; ni++)
#pragma unroll
            for (int j = 0; j < 4; j++) acc[mi][ni][j] = 0.f;

#define CMPNN(slot) { \
    const __bf16* As = lds + (slot) * 12288; \
    const __bf16* Bs = As + 8192; \
    bf16x8 av[4], bv[4]; \
    _Pragma("unroll") for (int mi = 0; mi < 4; mi++) \
        av[mi] = *(const bf16x8*)&As[(wr * 64 + mi * 16 + l15) * 32 + l4 * 8]; \
    _Pragma("unroll") for (int ni = 0; ni < 4; ni++) \
        bv[ni] = *(const bf16x8*)&Bs[(wc * 64 + ni * 16 + l15) * 32 + l4 * 8]; \
    __builtin_amdgcn_s_setprio(1); \
    _Pragma("unroll") for (int mi = 0; mi < 4; mi++) \
        _Pragma("unroll") for (int ni = 0; ni < 4; ni++) \
            acc[mi][ni] = __builtin_amdgcn_mfma_f32_16x16x32_bf16(av[mi], bv[ni], acc[mi][ni], 0, 0, 0); \
    __builtin_amdgcn_s_setprio(0); }

    const int nkt = K >> 5;
    STGNN(0, 0); STGNN(1, 1); STGNN(2, 2);
    int kt = 0;
    for (; kt < nkt - 3; kt++) {
        VMCNT(6); RBAR();
        STGNN((kt + 3) & 3, kt + 3);
        CMPNN(kt & 3);
    }
    VMCNT(6); RBAR(); CMPNN(kt & 3); kt++;
    VMCNT(3); RBAR(); CMPNN(kt & 3); kt++;
    VMCNT(0); RBAR(); CMPNN(kt & 3);

#pragma unroll
    for (int mi = 0; mi < 4; mi++) {
#pragma unroll
        for (int j = 0; j < 4; j++) {
            int r = bx * 256 + wr * 64 + mi * 16 + l4 * 4 + j;
            if (r < cnt) {
                if constexpr (MODE == 0) {
                    size_t orow = (size_t)r * 1024;
#pragma unroll
                    for (int ni = 0; ni < 4; ni++) {
                        int c = by * 128 + wc * 64 + ni * 16 + l15;
                        outB16[orow + c] = (__bf16)acc[mi][ni][j];
                    }
                } else if constexpr (MODE == 1) {
                    int sr = gofs + r;
                    float w = wrow[sr];
                    size_t orow = (size_t)(8192 + sr) * 1024;
#pragma unroll
                    for (int ni = 0; ni < 4; ni++) {
                        int c = by * 128 + wc * 64 + ni * 16 + l15;
                        outB16[orow + c] = (__bf16)(w * acc[mi][ni][j]);
                    }
                } else {
                    size_t orow = (size_t)r * 1024;
#pragma unroll
                    for (int ni = 0; ni < 4; ni++) {
                        int c = by * 128 + wc * 64 + ni * 16 + l15;
                        outF32[orow + c] = acc[mi][ni][j];
                    }
                }
            }
        }
    }
#undef STGNN
#undef CMPNN
}

// ---------------- combine: cb[t] = bf16( ys[t] + yr[islot0] + yr[islot1] ) ----------------
__global__ __launch_bounds__(256) void combine_k(
    const __bf16* __restrict__ ybuf, const int* __restrict__ islot, __bf16* __restrict__ cb)
{
    int tid = threadIdx.x;
    int row = blockIdx.x * 2 + (tid >> 7);
    int c8 = (tid & 127) * 8;
    int s0 = islot[2 * row], s1 = islot[2 * row + 1];
    bf16x8 vs = *(const bf16x8*)&ybuf[(size_t)row * 1024 + c8];
    bf16x8 v0 = *(const bf16x8*)&ybuf[(size_t)(8192 + s0) * 1024 + c8];
    bf16x8 v1 = *(const bf16x8*)&ybuf[(size_t)(8192 + s1) * 1024 + c8];
    bf16x8 o;
#pragma unroll
    for (int j = 0; j < 8; j++) o[j] = (__bf16)((float)vs[j] + (float)v0[j] + (float)v1[j]);
    *(bf16x8*)&cb[(size_t)row * 1024 + c8] = o;
}

extern "C" void kernel_launch(void* const* d_in, const int* in_sizes, int n_in,
                              void* d_out, int out_size, void* d_ws, size_t ws_size,
                              hipStream_t stream) {
    const float* x    = (const float*)d_in[0];
    const float* w1s  = (const float*)d_in[1];
    const float* w2s  = (const float*)d_in[2];
    const float* w3s  = (const float*)d_in[3];
    const float* w1r  = (const float*)d_in[4];
    const float* w2r  = (const float*)d_in[5];
    const float* w3r  = (const float*)d_in[6];
    const float* gate = (const float*)d_in[7];
    const float* outw = (const float*)d_in[8];
    float* out = (float*)d_out;

    char* ws = (char*)d_ws;
    float* auxp = (float*)ws;
    float* auxf = auxp + 8;
    int*   rcnt = (int*)(ws + 64);
    int*   curs = rcnt + 8;
    size_t off = 256;
    __bf16* xb    = (__bf16*)(ws + off); off += 16777216;   // [8192][1024]
    __bf16* W13T  = (__bf16*)(ws + off); off += 67108864;   // 32768 rows x 1024
    __bf16* W2T   = (__bf16*)(ws + off); off += 33554432;   // shared 1024x4096 + 6 x 1024x2048 (B^T)
    __bf16* OutWT = (__bf16*)(ws + off); off += 2097152;    // [1024][1024]
    __bf16* gbuf  = (__bf16*)(ws + off); off += 67108864;   // shared 8192x4096 OR routed 16384x2048
    __bf16* cb    = gbuf;                                   // alias: cb live only after gbuf dead
    __bf16* ybuf  = (__bf16*)(ws + off); off += 50331648;   // 24576 rows x 1024 (ys | yr)
    int*   tke   = (int*)(ws + off);   off += 65536;
    float* tkw   = (float*)(ws + off); off += 65536;
    int*   perm  = (int*)(ws + off);   off += 65536;
    float* wrow  = (float*)(ws + off); off += 65536;
    int*   islot = (int*)(ws + off);   off += 65536;
    int*   goffp = (int*)(ws + off);   off += 64;
    int*   gcntp = (int*)(ws + off);   off += 64;

    hipMemsetAsync(d_ws, 0, 256, stream);

    dim3 b256(256), b512(512);
    tcvt_k<<<dim3(64, 64, 25), b256, 0, stream>>>(w1s, w2s, w3s, w1r, w2r, w3r, outw, W13T, W2T, OutWT);
    router_k<<<dim3(512), b256, 0, stream>>>(x, gate, xb, tke, tkw, auxp, auxf, rcnt);
    offsets_k<<<dim3(1), dim3(64), 0, stream>>>(rcnt, goffp, gcntp);
    scatter_k<<<dim3(32), b256, 0, stream>>>(tke, tkw, goffp, curs, perm, wrow, islot);
    auxfin_k<<<dim3(1), dim3(64), 0, stream>>>(auxp, auxf, out);

    // shared concat expert: x -> gbuf[8192][4096] -> ys
    gemm13_k<1><<<dim3(32, 32, 1), b512, 0, stream>>>(xb, W13T, gbuf, goffp, gcntp, perm);
    gemmNN_k<0><<<dim3(32, 8, 1), b512, 0, stream>>>(gbuf, W2T, ybuf, nullptr, wrow, goffp, gcntp, 4096);
    // routed experts: x(gathered) -> gbuf[16384][2048] -> yr (scaled)
    gemm13_k<0><<<dim3(32, 16, 6), b512, 0, stream>>>(xb, W13T, gbuf, goffp, gcntp, perm);
    gemmNN_k<1><<<dim3(64, 8, 6), b512, 0, stream>>>(gbuf, W2T + (size_t)4096 * 1024, ybuf, nullptr, wrow, goffp, gcntp, 2048);

    combine_k<<<dim3(4096), b256, 0, stream>>>(ybuf, islot, cb);
    gemmNN_k<2><<<dim3(32, 8, 1), b512, 0, stream>>>(cb, OutWT, nullptr, out, wrow, goffp, gcntp, 1024);
}